// Round 1
// 271.284 us; speedup vs baseline: 1.0150x; 1.0150x over previous
//
#include <hip/hip_runtime.h>
#include <math.h>

// SpectralConv3d via DHT identities:
//   r = Re(F) - Im(G);  ||r||^2 = (N^3/2)(2*sum x^2 + c1 - c2)  [cross term = 0]
//   corner: n3->k3 + n2->k2 fused (k_fwd1), n1->k1 (k_fwd2s)
//   mix: conv = 0.5*sum_i[(x+xn)w + (x-xn)wn];  ||Y||^2 = (N^3/2)(2*sum conv^2 + conv000^2)
//   expand: n1->k1 (A1), n2->k2 (B2, LDS), n3->k3 with C1/C2 fused flip term.
//
// R1 changes vs 274.5us baseline:
//   - k_fwd1/k_fwd2s: twiddle recurrences (8 VALU/elem) -> LDS table broadcast reads
//     (wave-uniform ds_read_b128/b64) -- moves rotation work off the VALU pipe.
//   - k_fwd2s: grid 2x128 -> 4x128 (1 -> 2 blocks/CU).
//   - k_mixA: grid 128 -> 256 (split n2-halves; full-GPU coverage); second-norm
//     becomes 2 partials Q0/Q1, finalized per-block in k_expBC.

constexpr int NT = 262144;  // 64^3
constexpr float TWOPI_64 = 0.09817477042468103f;  // 2*pi/64

// ws float offsets:
//   S     [128][64][2][64][2] : 2097152 at 0        (8.4 MB)
//   red1p [128][33][3]        : 12672   at 2097152
//   xh    [128][512]          : 65536   at 2109824
//   inv2q [128][2]            : 256     at 2175360
//   A1    [128][8192]         : 1048576 at 2175616  (total ~12.9 MB)

// ---------------- K1: stage1 (n3->k3) + stage2 (n2->k2) + norm partials ----------------
__global__ __launch_bounds__(256) void k_fwd1(const float* __restrict__ x,
                                              float* __restrict__ S,
                                              float* __restrict__ red1p) {
  __shared__ float As[64 * 68];   // pad 68: 16B-aligned rows for ds_read_b128
  __shared__ float Bs[64 * 68];
  __shared__ float PL[32 * 65];   // stage1 output: rr = row*16 + f*8 + k3
  __shared__ float tw1[1024];     // [n3 64][k3q 4][c(k3q),s(k3q),c(k3q+4),s(k3q+4)]
  __shared__ float rsm[12];
  const int t = threadIdx.x;
  const int j = blockIdx.x;       // 0..32
  const int bc = blockIdx.y;      // 0..127
  const int n1a = j, n1b = (64 - j) & 63;
  const bool paired = (n1a != n1b);
  // twiddle table: tw1[n3*16 + k3q*4 + {0..3}] = {cos,sin for k3q, cos,sin for k3q+4}
  for (int u = t; u < 1024; u += 256) {
    int n3 = u >> 4, k3q = (u >> 2) & 3, jj = u & 3;
    int k3 = k3q + ((jj >> 1) << 2);
    float ang = TWOPI_64 * (float)((k3 * n3) & 63);
    tw1[u] = (jj & 1) ? sinf(ang) : cosf(ang);
  }
  const float4* xa4 = (const float4*)(x + ((size_t)bc << 18) + (n1a << 12));
  const float4* xb4 = (const float4*)(x + ((size_t)bc << 18) + (n1b << 12));
  float ssp = 0.f;
  for (int q = 0; q < 4; ++q) {
    int l4 = t + (q << 8);
    int fl = l4 << 2;
    int r = fl >> 6, c = fl & 63;
    float4 va = xa4[l4], vb = xb4[l4];
    *(float4*)&As[r * 68 + c] = va;
    *(float4*)&Bs[r * 68 + c] = vb;
    ssp += va.x * va.x + va.y * va.y + va.z * va.z + va.w * va.w;
    if (paired) ssp += vb.x * vb.x + vb.y * vb.y + vb.z * vb.z + vb.w * vb.w;
  }
  __syncthreads();
  const int n2 = t & 63;
  const int k3q = t >> 6;         // wave-uniform -> twiddle reads broadcast
  {  // stage 1: contract n3 for k3q,k3q+4 over rows A,B; twiddles from LDS table
    float reA0 = 0, imA0 = 0, reA1 = 0, imA1 = 0;
    float reB0 = 0, imB0 = 0, reB1 = 0, imB1 = 0;
    const float4* Ar = (const float4*)&As[n2 * 68];
    const float4* Br = (const float4*)&Bs[n2 * 68];
    const float4* T4 = (const float4*)tw1;
    for (int m = 0; m < 16; ++m) {
      float4 va = Ar[m], vb = Br[m];
      float av[4] = {va.x, va.y, va.z, va.w};
      float bv[4] = {vb.x, vb.y, vb.z, vb.w};
#pragma unroll
      for (int e = 0; e < 4; ++e) {
        float4 tw = T4[(m << 4) + (e << 2) + k3q];   // broadcast b128
        float a = av[e], b = bv[e];
        reA0 += a * tw.x; imA0 -= a * tw.y;
        reB0 += b * tw.x; imB0 -= b * tw.y;
        reA1 += a * tw.z; imA1 -= a * tw.w;
        reB1 += b * tw.z; imB1 -= b * tw.w;
      }
    }
    PL[(k3q) * 65 + n2] = reA0;       PL[(8 + k3q) * 65 + n2] = imA0;
    PL[(16 + k3q) * 65 + n2] = reB0;  PL[(24 + k3q) * 65 + n2] = imB0;
    PL[(4 + k3q) * 65 + n2] = reA1;   PL[(12 + k3q) * 65 + n2] = imA1;
    PL[(20 + k3q) * 65 + n2] = reB1;  PL[(28 + k3q) * 65 + n2] = imB1;
  }
  // norm partials c1,c2 (ss done at load)
  float c1p = 0.f, c2p = 0.f;
  for (int q = 0; q < 16; ++q) {
    int l = t + (q << 8);
    int r = l >> 6, c = l & 63;
    float a = As[r * 68 + c];
    int m2 = (64 - r) & 63;
    int m3 = (64 - c) & 63;
    int m3b = (62 - c) & 63;
    c1p += a * Bs[m2 * 68 + m3];
    c2p += a * Bs[m2 * 68 + m3b];
  }
  if (paired) { c1p *= 2.f; c2p *= 2.f; }
  for (int off = 32; off; off >>= 1) {
    ssp += __shfl_down(ssp, off);
    c1p += __shfl_down(c1p, off);
    c2p += __shfl_down(c2p, off);
  }
  const int lane = t & 63, wid = t >> 6;
  if (lane == 0) { rsm[wid * 3] = ssp; rsm[wid * 3 + 1] = c1p; rsm[wid * 3 + 2] = c2p; }
  __syncthreads();   // covers PL writes + rsm
  if (t == 0) {
    red1p[((size_t)bc * 33 + j) * 3 + 0] = rsm[0] + rsm[3] + rsm[6] + rsm[9];
    red1p[((size_t)bc * 33 + j) * 3 + 1] = rsm[1] + rsm[4] + rsm[7] + rsm[10];
    red1p[((size_t)bc * 33 + j) * 3 + 2] = rsm[2] + rsm[5] + rsm[8] + rsm[11];
  }
  {  // stage 2: contract n2 for 8 k2; twiddles from tw1 (8 distinct banks, conflict-free)
    const int k2 = t & 7;
    const int rr = t >> 3;
    const int row = rr >> 4, f = (rr >> 3) & 1, k3 = rr & 7;
    float re = 0.f, im = 0.f;
    const float* pr = &PL[rr * 65];
    const int tb = ((k2 & 3) << 2) + ((k2 >> 2) << 1);
#pragma unroll 4
    for (int n2i = 0; n2i < 64; ++n2i) {
      float v = pr[n2i];
      const float2 cs = *(const float2*)&tw1[(n2i << 4) + tb];
      re += v * cs.x; im -= v * cs.y;
    }
    const int n1row = row ? n1b : n1a;
    ((float2*)S)[(((size_t)bc * 64 + n1row) * 2 + f) * 64 + k2 * 8 + k3] =
        make_float2(re, im);
  }
}

// ---------------- K2: stage3 (n1->k1) + corner r + normalize ----------------
// grid (4,128): h splits the k2k3 range 4 ways (2 blocks/CU); both f halves in-block.
__global__ __launch_bounds__(256) void k_fwd2s(const float* __restrict__ S,
                                               const float* __restrict__ red1p,
                                               float* __restrict__ xh) {
  __shared__ float2 U3L[256];     // [f][k1 8][kkl 16]
  __shared__ float2 tw[8 * 66];   // [k1][n1] pad 66 -> bank spread
  __shared__ float rbuf[99];
  const int t = threadIdx.x;
  const int h = blockIdx.x;       // 0..3
  const int bc = blockIdx.y;
  for (int u = t; u < 512; u += 256) {
    int k1 = u >> 6, n1 = u & 63;
    float ang = TWOPI_64 * (float)((k1 * n1) & 63);
    tw[k1 * 66 + n1] = make_float2(cosf(ang), sinf(ang));
  }
  if (t < 99) rbuf[t] = red1p[(size_t)bc * 99 + t];
  __syncthreads();
  {
    const int kkl = t & 15;
    const int f = (t >> 4) & 1;
    const int k1 = t >> 5;          // one k1 per thread
    const int rr2 = f * 64 + h * 16 + kkl;
    const float2* Sb = (const float2*)(S + ((size_t)bc << 14));
    const float2* tk = &tw[k1 * 66];
    float re = 0.f, im = 0.f;
#pragma unroll 4
    for (int n1 = 0; n1 < 64; ++n1) {
      float2 ab = Sb[(n1 << 7) + rr2];
      float2 cs = tk[n1];
      re += ab.x * cs.x + ab.y * cs.y;
      im += ab.y * cs.x - ab.x * cs.y;
    }
    U3L[f * 128 + k1 * 16 + kkl] = make_float2(re, im);
  }
  __syncthreads();
  float ss = 0.f, c1 = 0.f, c2 = 0.f;
  for (int jj = 0; jj < 33; ++jj) {
    ss += rbuf[jj * 3];
    c1 += rbuf[jj * 3 + 1];
    c2 += rbuf[jj * 3 + 2];
  }
  float nsq = 0.5f * (float)NT * (2.f * ss + c1 - c2);
  float inv1 = nsq > 0.f ? rsqrtf(nsq) : 0.f;
  if (t < 128) {
    const int k1 = t >> 4, kkl = t & 15;
    const int kk = h * 16 + kkl;
    const int k3 = kk & 7;
    float2 U = U3L[k1 * 16 + kkl];
    float2 V = U3L[128 + k1 * 16 + kkl];
    float2 cs = tw[k3 * 66 + 1];    // (cos(th*k3), sin(th*k3))
    float r = U.x - V.y - cs.y * (U.x + V.y) - cs.x * (U.y - V.x);
    xh[(size_t)bc * 512 + k1 * 64 + kk] = r * inv1;
  }
}

// ---------------- K3: channel mixing + expansion stage A + norm partials ----------------
// grid 256: 2 blocks per (b,o), split by n2-half of (n2,n3) columns.
__global__ __launch_bounds__(256) void k_mixA(const float* __restrict__ xh,
                                              const float* __restrict__ w,
                                              float* __restrict__ A1,
                                              float* __restrict__ inv2q) {
  __shared__ float xsh[16384];    // 64 KB: full xh slice for this b
  __shared__ float convL[8 * 33]; // [n1][col32] pad 33
  __shared__ float c64v[64], s64v[64];
  __shared__ float psum[4];
  const int t = threadIdx.x;
  const int bh = blockIdx.x;
  const int h = bh & 1;
  const int bc2 = bh >> 1;
  const int b = bc2 >> 5, o = bc2 & 31;
  if (t < 64) { float ang = TWOPI_64 * t; c64v[t] = cosf(ang); s64v[t] = sinf(ang); }
  const float4* xb4 = (const float4*)(xh + ((size_t)b << 14));
  float4* xs4 = (float4*)xsh;
  for (int q = 0; q < 16; ++q) xs4[t + (q << 8)] = xb4[t + (q << 8)];
  __syncthreads();
  // mix: one k per thread (256 k's per block = 8 n1 x 32 cols)
  const int n1m = t >> 5;
  const int col32 = t & 31;
  const int col = (h << 5) + col32;
  const int n2 = col >> 3, n3 = col & 7;
  const int k = (n1m << 6) + col;
  const int nk = (((8 - n1m) & 7) << 6) + (((8 - n2) & 7) << 3) + ((8 - n3) & 7);
  float acc = 0.f;
  const float* wb = w + ((size_t)o << 9);
#pragma unroll 4
  for (int i = 0; i < 32; ++i) {
    const float* wr = wb + ((size_t)i << 14);
    float xa = xsh[(i << 9) + k], xn = xsh[(i << 9) + nk];
    acc += (xa + xn) * wr[k] + (xa - xn) * wr[nk];
  }
  const float cval = 0.5f * acc;
  convL[n1m * 33 + col32] = cval;
  // second-norm partial: Q_h = 2*sum(conv^2 over this half) (+ c000^2 for h==0)
  float p = cval * cval;
  for (int off = 32; off; off >>= 1) p += __shfl_down(p, off);
  if ((t & 63) == 0) psum[t >> 6] = p;
  __syncthreads();   // covers convL + psum
  if (t == 0) {
    float Q = 2.f * (psum[0] + psum[1] + psum[2] + psum[3]);
    if (h == 0) { float c000 = convL[0]; Q += c000 * c000; }
    inv2q[bc2 * 2 + h] = Q;
  }
  // stage A: n1 -> k1 for this block's 32 cols; 8 k1 per thread
  const int q8 = t >> 5;
  float cv[8];
#pragma unroll
  for (int n1i = 0; n1i < 8; ++n1i) cv[n1i] = convL[n1i * 33 + col32];
  float2* A1p = (float2*)(A1 + ((size_t)bc2 << 13));
  for (int it = 0; it < 8; ++it) {
    const int k1 = q8 + (it << 3);
    float re = 0.f, im = 0.f;
#pragma unroll
    for (int n1i = 0; n1i < 8; ++n1i) {
      int a = (k1 * n1i) & 63;
      re += cv[n1i] * c64v[a];
      im -= cv[n1i] * s64v[a];
    }
    A1p[(k1 << 6) + col] = make_float2(re, im);
  }
}

// ---------------- K4: expansion stages B+C fused; vector LDS reads ----------------
__global__ __launch_bounds__(256) void k_expBC(const float* __restrict__ A1,
                                               const float* __restrict__ inv2q,
                                               float* __restrict__ out) {
  __shared__ float arow[128];
  __shared__ float B2[64 * 20];   // [k2][f*8+n3] pad 20: rows 16B-aligned, groups disjoint
  __shared__ float c64v[64], s64v[64];
  const int t = threadIdx.x;
  const int k1 = blockIdx.x;
  const int bc2 = blockIdx.y;
  const float q0 = inv2q[bc2 * 2], q1 = inv2q[bc2 * 2 + 1];
  if (t < 64) { float ang = TWOPI_64 * t; c64v[t] = cosf(ang); s64v[t] = sinf(ang); }
  if (t < 128) arow[t] = A1[((size_t)bc2 << 13) + (k1 << 7) + t];
  __syncthreads();
  {  // stage B: contract n2 for all 64 k2; thread = (k2, f, n3-quad); g wave-uniform
    const int k2 = t & 63;
    const int g = t >> 6;
    const int f = g & 1;
    const int n3h = (g >> 1) << 2;
    float acc[4] = {0, 0, 0, 0};
    for (int n2i = 0; n2i < 8; ++n2i) {
      int a_ = (k2 * n2i) & 63;
      float tc = c64v[a_], ts = s64v[a_];
      const float4* ar4 = (const float4*)&arow[((n2i << 3) + n3h) << 1];
      float4 p0 = ar4[0];   // a0,b0,a1,b1  (uniform -> broadcast b128)
      float4 p1 = ar4[1];   // a2,b2,a3,b3
      if (f == 0) {
        acc[0] += p0.x * tc + p0.y * ts;
        acc[1] += p0.z * tc + p0.w * ts;
        acc[2] += p1.x * tc + p1.y * ts;
        acc[3] += p1.z * tc + p1.w * ts;
      } else {
        acc[0] += p0.y * tc - p0.x * ts;
        acc[1] += p0.w * tc - p0.z * ts;
        acc[2] += p1.y * tc - p1.x * ts;
        acc[3] += p1.w * tc - p1.z * ts;
      }
    }
    *(float4*)&B2[k2 * 20 + (f << 3) + n3h] = make_float4(acc[0], acc[1], acc[2], acc[3]);
  }
  __syncthreads();
  {  // stage C: contract n3 for all k3 with fused flip coefficients; b128 row reads
    const int k3 = t & 63;
    const int wid = t >> 6;
    float C1r[8], C2r[8];
#pragma unroll
    for (int n3 = 0; n3 < 8; ++n3) {
      int a0 = (k3 * n3) & 63;
      int a1 = (k3 * (n3 + 1)) & 63;
      C1r[n3] = c64v[a0] - s64v[a1];
      C2r[n3] = s64v[a0] - c64v[a1];
    }
    float nsq = 0.5f * (float)NT * (q0 + q1);
    const float sc = nsq > 0.f ? 1.f / (sqrtf(nsq) * (float)NT) : 0.f;
    float* dst = out + ((size_t)bc2 << 18) + (k1 << 12);
    for (int it = 0; it < 16; ++it) {
      int k2 = (wid << 4) + it;
      const float4* br4 = (const float4*)&B2[k2 * 20];   // uniform -> broadcast b128
      float4 r0 = br4[0], r1 = br4[1], r2 = br4[2], r3 = br4[3];
      float acc = r0.x * C1r[0] + r0.y * C1r[1] + r0.z * C1r[2] + r0.w * C1r[3]
                + r1.x * C1r[4] + r1.y * C1r[5] + r1.z * C1r[6] + r1.w * C1r[7]
                + r2.x * C2r[0] + r2.y * C2r[1] + r2.z * C2r[2] + r2.w * C2r[3]
                + r3.x * C2r[4] + r3.y * C2r[5] + r3.z * C2r[6] + r3.w * C2r[7];
      dst[(k2 << 6) + k3] = acc * sc;
    }
  }
}

extern "C" void kernel_launch(void* const* d_in, const int* in_sizes, int n_in,
                              void* d_out, int out_size, void* d_ws, size_t ws_size,
                              hipStream_t stream) {
  const float* x = (const float*)d_in[0];
  const float* w = (const float*)d_in[1];
  float* out = (float*)d_out;
  float* ws = (float*)d_ws;
  float* S     = ws;
  float* red1p = ws + 2097152;
  float* xh    = ws + 2109824;
  float* inv2q = ws + 2175360;
  float* A1    = ws + 2175616;

  k_fwd1 <<<dim3(33, 128), 256, 0, stream>>>(x, S, red1p);
  k_fwd2s<<<dim3(4, 128),  256, 0, stream>>>(S, red1p, xh);
  k_mixA <<<dim3(256),     256, 0, stream>>>(xh, w, A1, inv2q);
  k_expBC<<<dim3(64, 128), 256, 0, stream>>>(A1, inv2q, out);
}